// Round 17
// baseline (188.468 us; speedup 1.0000x reference)
//
#include <hip/hip_runtime.h>
#include <cfloat>
#include <cstdint>

#define NPTS 65536
#define DIM 256
#define NC 16
#define KSEL 2048
#define VMAX 4608
#define EPSV 1e-6f

// ws layout (bytes):
//     0 : float sums[16*256]   (16384)
// 16384 : int counts[16]       (64)
// 16512 : int offsets[16]      (64)
// 16576 : float csq[16]        (64)
// 16640 : float pos_stat[16]   (64)
// 16704 : float neg_stat[256]  (1024)
// 17728 : float centers[4096]  (16384)
// 34112 : int bhist[256*16]    (16384)
// 65536 : float Dmat[16*65536] (4 MB) -- also start of partials[1024][4096] (16 MB) pre-k_dist
// 16842752 : int slots[65536]  (256 KB)

__global__ void __launch_bounds__(256) k_hist(const int* __restrict__ y,
                                              int* __restrict__ bhist) {
  __shared__ int h[NC];
  int t = threadIdx.x;
  if (t < NC) h[t] = 0;
  __syncthreads();
  int p = blockIdx.x * 256 + t;
  atomicAdd(&h[y[p * 3 + 2]], 1);
  __syncthreads();
  if (t < NC) bhist[blockIdx.x * NC + t] = h[t];
}

// Scan bhist per class across 256 chunks; emits counts/offsets; zeroes gsums.
__global__ void __launch_bounds__(256) k_scan(int* __restrict__ bhist,
                                              int* __restrict__ counts,
                                              int* __restrict__ offsets,
                                              float* __restrict__ gsums) {
  __shared__ int lh[256 * NC];
  __shared__ int segbase[16][NC];
  __shared__ int totl[NC], offl[NC];
  int t = threadIdx.x;
  for (int u = t; u < NC * DIM; u += 256) gsums[u] = 0.f;
  for (int u = t; u < 256 * NC; u += 256) lh[u] = bhist[u];
  __syncthreads();
  int c = t & 15, g = t >> 4;
  int part = 0;
#pragma unroll
  for (int b = 0; b < 16; ++b) part += lh[(g * 16 + b) * NC + c];
  segbase[g][c] = part;
  __syncthreads();
  if (t < NC) {
    int tot = 0;
#pragma unroll
    for (int g2 = 0; g2 < 16; ++g2) tot += segbase[g2][t];
    totl[t] = tot;
    counts[t] = tot;
  }
  __syncthreads();
  if (t == 0) {
    int run = 0;
    for (int c2 = 0; c2 < NC; ++c2) { offl[c2] = run; offsets[c2] = run; run += totl[c2]; }
  }
  __syncthreads();
  if (t < NC) {
    int run = offl[t];
#pragma unroll
    for (int g2 = 0; g2 < 16; ++g2) { int tmp = segbase[g2][t]; segbase[g2][t] = run; run += tmp; }
  }
  __syncthreads();
  int run = segbase[g][c];
#pragma unroll
  for (int b = 0; b < 16; ++b) {
    int idx = (g * 16 + b) * NC + c;
    int tmp = lh[idx]; lh[idx] = run; run += tmp;
  }
  __syncthreads();
  for (int u = t; u < 256 * NC; u += 256) bhist[u] = lh[u];
}

// slot[p] = chunk base + stable rank, rank via 16 ballots (no serial loop).
__global__ void __launch_bounds__(256) k_slot(const int* __restrict__ y,
                                              const int* __restrict__ bbase,
                                              int* __restrict__ slots) {
  __shared__ int labs[256];
  __shared__ int wcnt[4][NC];
  int t = threadIdx.x;
  int chunk = blockIdx.x;
  labs[t] = y[(chunk * 256 + t) * 3 + 2];
  __syncthreads();
  int lab = labs[t];
  int lane = t & 63, w = t >> 6;
  unsigned long long mymask = 0;
#pragma unroll
  for (int c = 0; c < NC; ++c) {
    unsigned long long mk = __ballot(lab == c);
    if (lane == 0) wcnt[w][c] = __popcll(mk);
    if (lab == c) mymask = mk;
  }
  __syncthreads();
  int rank = __popcll(mymask & ((1ull << lane) - 1ull));
  for (int w2 = 0; w2 < w; ++w2) rank += wcnt[w2][lab];
  slots[chunk * 256 + t] = bbase[chunk * NC + lab] + rank;
}

#define ACC_CASE(C) case C: acc[C][0] += xv[u].x; acc[C][1] += xv[u].y; \
                            acc[C][2] += xv[u].z; acc[C][3] += xv[u].w; break;

// 1024 blocks x 64 rows; wave w owns rows [16w,16w+16). 32KB two-phase LDS
// combine (waves 0/1 write, waves 2/3 add) -> 4 blocks/CU, 16 waves/CU.
__global__ void __launch_bounds__(256, 4) k_accum(const float* __restrict__ x,
                                                  const int* __restrict__ y,
                                                  float* __restrict__ partials) {
  __shared__ int labs[64];
  __shared__ float red[2 * NC * DIM];  // 32 KB
  int t = threadIdx.x;
  int n0 = blockIdx.x * 64;
  if (t < 64) labs[t] = y[(n0 + t) * 3 + 2];
  __syncthreads();
  int w = t >> 6, m = t & 63;

  float acc[NC][4];
#pragma unroll
  for (int c = 0; c < NC; ++c)
#pragma unroll
    for (int j = 0; j < 4; ++j) acc[c][j] = 0.f;

  for (int r0 = 0; r0 < 16; r0 += 4) {
    float4 xv[4];
#pragma unroll
    for (int u = 0; u < 4; ++u)
      xv[u] = *(const float4*)(x + (size_t)(n0 + 16 * w + r0 + u) * DIM + 4 * m);
#pragma unroll
    for (int u = 0; u < 4; ++u) {
      int lab = __builtin_amdgcn_readfirstlane(labs[16 * w + r0 + u]);
      switch (lab) {
        ACC_CASE(0) ACC_CASE(1) ACC_CASE(2) ACC_CASE(3)
        ACC_CASE(4) ACC_CASE(5) ACC_CASE(6) ACC_CASE(7)
        ACC_CASE(8) ACC_CASE(9) ACC_CASE(10) ACC_CASE(11)
        ACC_CASE(12) ACC_CASE(13) ACC_CASE(14) ACC_CASE(15)
      }
    }
  }

  int half = w & 1;  // waves 0,1 -> phase A; waves 2,3 -> phase B (same half)
  if (w < 2) {
#pragma unroll
    for (int c = 0; c < NC; ++c)
#pragma unroll
      for (int j = 0; j < 4; ++j)
        red[half * (NC * DIM) + c * DIM + 4 * m + j] = acc[c][j];
  }
  __syncthreads();
  if (w >= 2) {
#pragma unroll
    for (int c = 0; c < NC; ++c)
#pragma unroll
      for (int j = 0; j < 4; ++j)
        red[half * (NC * DIM) + c * DIM + 4 * m + j] += acc[c][j];
  }
  __syncthreads();
  for (int u = t; u < NC * DIM; u += 256)
    partials[(size_t)blockIdx.x * (NC * DIM) + u] = red[u] + red[NC * DIM + u];
}

// 8 slices x 128 chunks each over 1024 partials; combined via atomicAdd.
__global__ void __launch_bounds__(256) k_reduce(const float* __restrict__ partials,
                                                float* __restrict__ gsums) {
  int tg = blockIdx.x * 256 + threadIdx.x;
  int u = tg & 4095;
  int s = tg >> 12;
  float acc = 0.f;
#pragma unroll 8
  for (int b = s * 128; b < s * 128 + 128; ++b)
    acc += partials[(size_t)b * (NC * DIM) + u];
  atomicAdd(&gsums[u], acc);
}

// 16 blocks, one class each: divide, write center row, wave-reduce csq.
__global__ void __launch_bounds__(256) k_centers(const float* __restrict__ gsums,
                                                 const int* __restrict__ gcounts,
                                                 float* __restrict__ centers,
                                                 float* __restrict__ csq) {
  __shared__ float wsum[4];
  int d = threadIdx.x, c = blockIdx.x;
  float v = gsums[c * DIM + d] / (float)gcounts[c] + EPSV;
  centers[c * DIM + d] = v;
  float q = v * v;
#pragma unroll
  for (int m = 1; m < 64; m <<= 1) q += __shfl_xor(q, m);
  if ((d & 63) == 0) wsum[d >> 6] = q;
  __syncthreads();
  if (d == 0) csq[c] = wsum[0] + wsum[1] + wsum[2] + wsum[3];
}

#define ST_CASE(S) case S: _Pragma("unroll") for (int i = 0; i < 2; ++i) { \
    float d2a = csql[2*S]   - 2.f * acc[i][2*S]   + xsq[i]; \
    float d2b = csql[2*S+1] - 2.f * acc[i][2*S+1] + xsq[i]; \
    int sl = slotL[bl + i]; \
    Dmat[(size_t)(2*S)   * NPTS + sl] = sqrtf(fmaxf(d2a, 0.f)); \
    Dmat[(size_t)(2*S+1) * NPTS + sl] = sqrtf(fmaxf(d2b, 0.f)); } break;

// P=2, L=8: wave = 16 points, block = 64 points, 1024 blocks, 16 waves/CU.
__global__ void __launch_bounds__(256, 4) k_dist(const float* __restrict__ x,
                                                 const float* __restrict__ centers,
                                                 const float* __restrict__ csq,
                                                 const int* __restrict__ slots,
                                                 float* __restrict__ Dmat) {
  __shared__ float4 cc[NC * 64];
  __shared__ float csql[NC];
  __shared__ int slotL[64];
  int t = threadIdx.x;
  const float4* cptr = (const float4*)centers;
  for (int u = t; u < NC * 64; u += 256) {
    int q = u & 63;
    int qs = (q & 0x38) | ((q & 7) ^ ((q >> 3) & 7));
    cc[(u & ~63) | qs] = cptr[u];
  }
  if (t < NC) csql[t] = csq[t];
  int pbase = blockIdx.x * 64;
  if (t < 64) slotL[t] = slots[pbase + t];
  __syncthreads();

  int wave = t >> 6, lane = t & 63;
  int s = lane & 7, pg = lane >> 3;
  int bl = wave * 16 + pg * 2;

  float4 xv[2][8];
#pragma unroll
  for (int i = 0; i < 2; ++i)
#pragma unroll
    for (int j = 0; j < 8; ++j)
      xv[i][j] = *(const float4*)(x + (size_t)(pbase + bl + i) * DIM + s * 32 + j * 4);

  float xsq[2];
#pragma unroll
  for (int i = 0; i < 2; ++i) {
    float q = 0.f;
#pragma unroll
    for (int j = 0; j < 8; ++j)
      q += xv[i][j].x * xv[i][j].x + xv[i][j].y * xv[i][j].y +
           xv[i][j].z * xv[i][j].z + xv[i][j].w * xv[i][j].w;
    xsq[i] = q;
  }

  float acc[2][NC];
#pragma unroll
  for (int i = 0; i < 2; ++i)
#pragma unroll
    for (int c = 0; c < NC; ++c) acc[i][c] = 0.f;

#pragma unroll
  for (int c = 0; c < NC; ++c)
#pragma unroll
    for (int j = 0; j < 8; ++j) {
      float4 cv = cc[c * 64 + s * 8 + (j ^ s)];
#pragma unroll
      for (int i = 0; i < 2; ++i)
        acc[i][c] += xv[i][j].x * cv.x + xv[i][j].y * cv.y +
                     xv[i][j].z * cv.z + xv[i][j].w * cv.w;
    }

#pragma unroll
  for (int i = 0; i < 2; ++i) {
    xsq[i] += __shfl_xor(xsq[i], 1);
    xsq[i] += __shfl_xor(xsq[i], 2);
    xsq[i] += __shfl_xor(xsq[i], 4);
#pragma unroll
    for (int c = 0; c < NC; ++c) {
      acc[i][c] += __shfl_xor(acc[i][c], 1);
      acc[i][c] += __shfl_xor(acc[i][c], 2);
      acc[i][c] += __shfl_xor(acc[i][c], 4);
    }
  }

  switch (s) {
    ST_CASE(0) ST_CASE(1) ST_CASE(2) ST_CASE(3)
    ST_CASE(4) ST_CASE(5) ST_CASE(6) ST_CASE(7)
  }
}

// Radix-select; bin location via wave-0 hierarchical find (no block scans).
__global__ void __launch_bounds__(512) k_select(const float* __restrict__ Dmat,
                                                const int* __restrict__ gcounts,
                                                const int* __restrict__ offsets,
                                                float* __restrict__ pos_stat,
                                                float* __restrict__ neg_stat) {
  __shared__ unsigned int keys[VMAX];
  __shared__ int hist[2048];
  __shared__ int bsel[2];
  __shared__ float wsumf[8];
  __shared__ int wsumi[8];
  int tid = threadIdx.x;
  int lane = tid & 63, wv = tid >> 6;
  int b = blockIdx.x;
  int ci = b >> 4, cl = b & 15;
  bool largest = (ci == cl);
  int cnt = gcounts[cl];
  if (cnt > VMAX) cnt = VMAX;
  int off = offsets[cl];
  const float* src = Dmat + (size_t)ci * NPTS + off;
  unsigned int inv = largest ? 0xFFFFFFFFu : 0u;
  for (int t = tid; t < cnt; t += 512) keys[t] = __float_as_uint(src[t]) ^ inv;
  __syncthreads();

  int target = KSEL;
  unsigned int pfx = 0;

  // ---- Level A: bits [21,32), 2048 bins ----
  for (int u = tid; u < 2048; u += 512) hist[u] = 0;
  __syncthreads();
  for (int t = tid; t < cnt; t += 512) atomicAdd(&hist[keys[t] >> 21], 1);
  __syncthreads();
  if (tid < 64) {
    int own = 0;
#pragma unroll
    for (int j = 0; j < 32; ++j) own += hist[lane * 32 + j];
    int incl = own;
    for (int o = 1; o < 64; o <<= 1) { int n = __shfl_up(incl, o); if (lane >= o) incl += n; }
    int excl = incl - own;
    unsigned long long mk = __ballot(excl < target && target <= incl);
    int sel = __ffsll((unsigned long long)mk) - 1;
    if (lane == sel) {
      int run = excl;
      for (int j = 0; j < 32; ++j) {
        int h = hist[lane * 32 + j];
        if (run < target && target <= run + h) { bsel[0] = lane * 32 + j; bsel[1] = target - run; }
        run += h;
      }
    }
  }
  __syncthreads();
  pfx = ((unsigned int)bsel[0]) << 21; target = bsel[1];
  __syncthreads();

  // ---- Level B: bits [10,21), 2048 bins ----
  for (int u = tid; u < 2048; u += 512) hist[u] = 0;
  __syncthreads();
  for (int t = tid; t < cnt; t += 512) {
    unsigned int k = keys[t];
    if ((k >> 21) == (pfx >> 21)) atomicAdd(&hist[(k >> 10) & 0x7FF], 1);
  }
  __syncthreads();
  if (tid < 64) {
    int own = 0;
#pragma unroll
    for (int j = 0; j < 32; ++j) own += hist[lane * 32 + j];
    int incl = own;
    for (int o = 1; o < 64; o <<= 1) { int n = __shfl_up(incl, o); if (lane >= o) incl += n; }
    int excl = incl - own;
    unsigned long long mk = __ballot(excl < target && target <= incl);
    int sel = __ffsll((unsigned long long)mk) - 1;
    if (lane == sel) {
      int run = excl;
      for (int j = 0; j < 32; ++j) {
        int h = hist[lane * 32 + j];
        if (run < target && target <= run + h) { bsel[0] = lane * 32 + j; bsel[1] = target - run; }
        run += h;
      }
    }
  }
  __syncthreads();
  pfx |= ((unsigned int)bsel[0]) << 10; target = bsel[1];
  __syncthreads();

  // ---- Level C: bits [0,10), 1024 bins ----
  for (int u = tid; u < 1024; u += 512) hist[u] = 0;
  __syncthreads();
  for (int t = tid; t < cnt; t += 512) {
    unsigned int k = keys[t];
    if ((k >> 10) == (pfx >> 10)) atomicAdd(&hist[k & 0x3FF], 1);
  }
  __syncthreads();
  if (tid < 64) {
    int own = 0;
#pragma unroll
    for (int j = 0; j < 16; ++j) own += hist[lane * 16 + j];
    int incl = own;
    for (int o = 1; o < 64; o <<= 1) { int n = __shfl_up(incl, o); if (lane >= o) incl += n; }
    int excl = incl - own;
    unsigned long long mk = __ballot(excl < target && target <= incl);
    int sel = __ffsll((unsigned long long)mk) - 1;
    if (lane == sel) {
      int run = excl;
      for (int j = 0; j < 16; ++j) {
        int h = hist[lane * 16 + j];
        if (run < target && target <= run + h) { bsel[0] = lane * 16 + j; }
        run += h;
      }
    }
  }
  __syncthreads();
  unsigned int T = pfx | (unsigned int)bsel[0];
  float fT = __uint_as_float(T ^ inv);

  // ---- pass 1: n_less, sum_less (wave reduce + 8-entry combine) ----
  int nl = 0; float sl = 0.f;
  for (int t = tid; t < cnt; t += 512) {
    unsigned int k = keys[t];
    if (k < T) { nl++; sl += __uint_as_float(k ^ inv); }
  }
#pragma unroll
  for (int m = 1; m < 64; m <<= 1) { nl += __shfl_xor(nl, m); sl += __shfl_xor(sl, m); }
  if (lane == 0) { wsumi[wv] = nl; wsumf[wv] = sl; }
  __syncthreads();
  int n_less = 0; float s_less = 0.f;
#pragma unroll
  for (int w2 = 0; w2 < 8; ++w2) { n_less += wsumi[w2]; s_less += wsumf[w2]; }
  float mean = (s_less + (float)(KSEL - n_less) * fT) / (float)KSEL;
  __syncthreads();

  // ---- pass 2: variance ----
  float sv = 0.f;
  for (int t = tid; t < cnt; t += 512) {
    unsigned int k = keys[t];
    if (k < T) { float d = __uint_as_float(k ^ inv) - mean; sv += d * d; }
  }
#pragma unroll
  for (int m = 1; m < 64; m <<= 1) sv += __shfl_xor(sv, m);
  if (lane == 0) wsumf[wv] = sv;
  __syncthreads();
  if (tid == 0) {
    float vs = 0.f;
#pragma unroll
    for (int w2 = 0; w2 < 8; ++w2) vs += wsumf[w2];
    float dT = fT - mean;
    float var = (vs + (float)(KSEL - n_less) * dT * dT) / (float)(KSEL - 1);
    if (largest) pos_stat[ci] = mean + 1.96f * sqrtf(var);
    else neg_stat[ci * 16 + cl] = mean - 1.96f * sqrtf(var);
  }
}

__global__ void __launch_bounds__(256) k_loss(const float* __restrict__ pos_stat,
                                              const float* __restrict__ neg_stat,
                                              float* __restrict__ out) {
  __shared__ float red[256];
  int t = threadIdx.x;
  int i = t >> 4, c = t & 15;
  float v = 0.f;
  if (i != c) v = fmaxf(1.0f + pos_stat[i] - neg_stat[t], 0.f);
  red[t] = v; __syncthreads();
  for (int st = 128; st > 0; st >>= 1) { if (t < st) red[t] += red[t + st]; __syncthreads(); }
  if (t == 0) out[0] = red[0];
}

extern "C" void kernel_launch(void* const* d_in, const int* in_sizes, int n_in,
                              void* d_out, int out_size, void* d_ws, size_t ws_size,
                              hipStream_t stream) {
  const float* x = (const float*)d_in[0];
  const int* y = (const int*)d_in[1];
  float* out = (float*)d_out;
  char* ws = (char*)d_ws;

  float* sums = (float*)(ws + 0);
  int* counts = (int*)(ws + 16384);
  int* offsets = (int*)(ws + 16512);
  float* csq = (float*)(ws + 16576);
  float* pos_stat = (float*)(ws + 16640);
  float* neg_stat = (float*)(ws + 16704);
  float* centers = (float*)(ws + 17728);
  int* bhist = (int*)(ws + 34112);
  float* Dmat = (float*)(ws + 65536);
  float* partials = (float*)(ws + 65536);   // [1024][4096] = 16 MB, consumed pre-k_dist
  int* slots = (int*)(ws + 16842752);

  k_hist<<<256, 256, 0, stream>>>(y, bhist);
  k_scan<<<1, 256, 0, stream>>>(bhist, counts, offsets, sums);
  k_slot<<<256, 256, 0, stream>>>(y, bhist, slots);
  k_accum<<<1024, 256, 0, stream>>>(x, y, partials);
  k_reduce<<<128, 256, 0, stream>>>(partials, sums);
  k_centers<<<16, 256, 0, stream>>>(sums, counts, centers, csq);
  k_dist<<<1024, 256, 0, stream>>>(x, centers, csq, slots, Dmat);
  k_select<<<256, 512, 0, stream>>>(Dmat, counts, offsets, pos_stat, neg_stat);
  k_loss<<<1, 256, 0, stream>>>(pos_stat, neg_stat, out);
}

// Round 19
// 92.033 us; speedup vs baseline: 2.0478x; 2.0478x over previous
//
#include <hip/hip_runtime.h>
#include <cfloat>
#include <cstdint>

#define NPTS 65536
#define DIM 256
#define NC 16
#define KSEL 2048
#define VMAX 4608
#define EPSV 1e-6f

// ws layout (bytes):
//     0 : float sums[16*256]   (16384)
// 16384 : int counts[16]       (64)
// 16512 : int offsets[16]      (64)
// 16576 : float csq[16]        (64)
// 16640 : float pos_stat[16]   (64)
// 16704 : float neg_stat[256]  (1024)
// 17728 : float centers[4096]  (16384)
// 34112 : int bhist[256*16]    (16384)
// 65536 : float Dmat[16*65536] (4 MB) -- also start of partials[1024][4096] (16 MB) pre-k_dist
// 16842752 : int slots[65536]  (256 KB)

__global__ void __launch_bounds__(256) k_hist(const int* __restrict__ y,
                                              int* __restrict__ bhist) {
  __shared__ int h[NC];
  int t = threadIdx.x;
  if (t < NC) h[t] = 0;
  __syncthreads();
  int p = blockIdx.x * 256 + t;
  atomicAdd(&h[y[p * 3 + 2]], 1);
  __syncthreads();
  if (t < NC) bhist[blockIdx.x * NC + t] = h[t];
}

// Scan bhist per class across 256 chunks; emits counts/offsets; zeroes gsums.
__global__ void __launch_bounds__(256) k_scan(int* __restrict__ bhist,
                                              int* __restrict__ counts,
                                              int* __restrict__ offsets,
                                              float* __restrict__ gsums) {
  __shared__ int lh[256 * NC];
  __shared__ int segbase[16][NC];
  __shared__ int totl[NC], offl[NC];
  int t = threadIdx.x;
  for (int u = t; u < NC * DIM; u += 256) gsums[u] = 0.f;
  for (int u = t; u < 256 * NC; u += 256) lh[u] = bhist[u];
  __syncthreads();
  int c = t & 15, g = t >> 4;
  int part = 0;
#pragma unroll
  for (int b = 0; b < 16; ++b) part += lh[(g * 16 + b) * NC + c];
  segbase[g][c] = part;
  __syncthreads();
  if (t < NC) {
    int tot = 0;
#pragma unroll
    for (int g2 = 0; g2 < 16; ++g2) tot += segbase[g2][t];
    totl[t] = tot;
    counts[t] = tot;
  }
  __syncthreads();
  if (t == 0) {
    int run = 0;
    for (int c2 = 0; c2 < NC; ++c2) { offl[c2] = run; offsets[c2] = run; run += totl[c2]; }
  }
  __syncthreads();
  if (t < NC) {
    int run = offl[t];
#pragma unroll
    for (int g2 = 0; g2 < 16; ++g2) { int tmp = segbase[g2][t]; segbase[g2][t] = run; run += tmp; }
  }
  __syncthreads();
  int run = segbase[g][c];
#pragma unroll
  for (int b = 0; b < 16; ++b) {
    int idx = (g * 16 + b) * NC + c;
    int tmp = lh[idx]; lh[idx] = run; run += tmp;
  }
  __syncthreads();
  for (int u = t; u < 256 * NC; u += 256) bhist[u] = lh[u];
}

// slot[p] = chunk base + stable rank, rank via 16 ballots (no serial loop).
__global__ void __launch_bounds__(256) k_slot(const int* __restrict__ y,
                                              const int* __restrict__ bbase,
                                              int* __restrict__ slots) {
  __shared__ int labs[256];
  __shared__ int wcnt[4][NC];
  int t = threadIdx.x;
  int chunk = blockIdx.x;
  labs[t] = y[(chunk * 256 + t) * 3 + 2];
  __syncthreads();
  int lab = labs[t];
  int lane = t & 63, w = t >> 6;
  unsigned long long mymask = 0;
#pragma unroll
  for (int c = 0; c < NC; ++c) {
    unsigned long long mk = __ballot(lab == c);
    if (lane == 0) wcnt[w][c] = __popcll(mk);
    if (lab == c) mymask = mk;
  }
  __syncthreads();
  int rank = __popcll(mymask & ((1ull << lane) - 1ull));
  for (int w2 = 0; w2 < w; ++w2) rank += wcnt[w2][lab];
  slots[chunk * 256 + t] = bbase[chunk * NC + lab] + rank;
}

#define ACC_CASE(C) case C: acc[C][0] += xv[u].x; acc[C][1] += xv[u].y; \
                            acc[C][2] += xv[u].z; acc[C][3] += xv[u].w; break;

// 1024 blocks x 64 rows; wave w owns rows [16w,16w+16). 32KB two-phase LDS
// combine. NOTE: no min-waves launch_bounds arg — (256,4) clamped VGPR to 64
// and spilled acc[16][4] to scratch (R17: FETCH 152MB, WRITE 407MB, 185us).
__global__ void __launch_bounds__(256) k_accum(const float* __restrict__ x,
                                               const int* __restrict__ y,
                                               float* __restrict__ partials) {
  __shared__ int labs[64];
  __shared__ float red[2 * NC * DIM];  // 32 KB
  int t = threadIdx.x;
  int n0 = blockIdx.x * 64;
  if (t < 64) labs[t] = y[(n0 + t) * 3 + 2];
  __syncthreads();
  int w = t >> 6, m = t & 63;

  float acc[NC][4];
#pragma unroll
  for (int c = 0; c < NC; ++c)
#pragma unroll
    for (int j = 0; j < 4; ++j) acc[c][j] = 0.f;

  for (int r0 = 0; r0 < 16; r0 += 4) {
    float4 xv[4];
#pragma unroll
    for (int u = 0; u < 4; ++u)
      xv[u] = *(const float4*)(x + (size_t)(n0 + 16 * w + r0 + u) * DIM + 4 * m);
#pragma unroll
    for (int u = 0; u < 4; ++u) {
      int lab = __builtin_amdgcn_readfirstlane(labs[16 * w + r0 + u]);
      switch (lab) {
        ACC_CASE(0) ACC_CASE(1) ACC_CASE(2) ACC_CASE(3)
        ACC_CASE(4) ACC_CASE(5) ACC_CASE(6) ACC_CASE(7)
        ACC_CASE(8) ACC_CASE(9) ACC_CASE(10) ACC_CASE(11)
        ACC_CASE(12) ACC_CASE(13) ACC_CASE(14) ACC_CASE(15)
      }
    }
  }

  int half = w & 1;  // waves 0,1 -> write; waves 2,3 -> add (same half)
  if (w < 2) {
#pragma unroll
    for (int c = 0; c < NC; ++c)
#pragma unroll
      for (int j = 0; j < 4; ++j)
        red[half * (NC * DIM) + c * DIM + 4 * m + j] = acc[c][j];
  }
  __syncthreads();
  if (w >= 2) {
#pragma unroll
    for (int c = 0; c < NC; ++c)
#pragma unroll
      for (int j = 0; j < 4; ++j)
        red[half * (NC * DIM) + c * DIM + 4 * m + j] += acc[c][j];
  }
  __syncthreads();
  for (int u = t; u < NC * DIM; u += 256)
    partials[(size_t)blockIdx.x * (NC * DIM) + u] = red[u] + red[NC * DIM + u];
}

// 8 slices x 128 chunks each over 1024 partials; combined via atomicAdd.
__global__ void __launch_bounds__(256) k_reduce(const float* __restrict__ partials,
                                                float* __restrict__ gsums) {
  int tg = blockIdx.x * 256 + threadIdx.x;
  int u = tg & 4095;
  int s = tg >> 12;
  float acc = 0.f;
#pragma unroll 8
  for (int b = s * 128; b < s * 128 + 128; ++b)
    acc += partials[(size_t)b * (NC * DIM) + u];
  atomicAdd(&gsums[u], acc);
}

// 16 blocks, one class each: divide, write center row, wave-reduce csq.
__global__ void __launch_bounds__(256) k_centers(const float* __restrict__ gsums,
                                                 const int* __restrict__ gcounts,
                                                 float* __restrict__ centers,
                                                 float* __restrict__ csq) {
  __shared__ float wsum[4];
  int d = threadIdx.x, c = blockIdx.x;
  float v = gsums[c * DIM + d] / (float)gcounts[c] + EPSV;
  centers[c * DIM + d] = v;
  float q = v * v;
#pragma unroll
  for (int m = 1; m < 64; m <<= 1) q += __shfl_xor(q, m);
  if ((d & 63) == 0) wsum[d >> 6] = q;
  __syncthreads();
  if (d == 0) csq[c] = wsum[0] + wsum[1] + wsum[2] + wsum[3];
}

#define ST_CASE(S) case S: _Pragma("unroll") for (int i = 0; i < 2; ++i) { \
    float d2a = csql[2*S]   - 2.f * acc[i][2*S]   + xsq[i]; \
    float d2b = csql[2*S+1] - 2.f * acc[i][2*S+1] + xsq[i]; \
    int sl = slotL[bl + i]; \
    Dmat[(size_t)(2*S)   * NPTS + sl] = sqrtf(fmaxf(d2a, 0.f)); \
    Dmat[(size_t)(2*S+1) * NPTS + sl] = sqrtf(fmaxf(d2b, 0.f)); } break;

// P=2, L=8: wave = 16 points, block = 64 points, 1024 blocks, 16 waves/CU.
__global__ void __launch_bounds__(256, 4) k_dist(const float* __restrict__ x,
                                                 const float* __restrict__ centers,
                                                 const float* __restrict__ csq,
                                                 const int* __restrict__ slots,
                                                 float* __restrict__ Dmat) {
  __shared__ float4 cc[NC * 64];
  __shared__ float csql[NC];
  __shared__ int slotL[64];
  int t = threadIdx.x;
  const float4* cptr = (const float4*)centers;
  for (int u = t; u < NC * 64; u += 256) {
    int q = u & 63;
    int qs = (q & 0x38) | ((q & 7) ^ ((q >> 3) & 7));
    cc[(u & ~63) | qs] = cptr[u];
  }
  if (t < NC) csql[t] = csq[t];
  int pbase = blockIdx.x * 64;
  if (t < 64) slotL[t] = slots[pbase + t];
  __syncthreads();

  int wave = t >> 6, lane = t & 63;
  int s = lane & 7, pg = lane >> 3;
  int bl = wave * 16 + pg * 2;

  float4 xv[2][8];
#pragma unroll
  for (int i = 0; i < 2; ++i)
#pragma unroll
    for (int j = 0; j < 8; ++j)
      xv[i][j] = *(const float4*)(x + (size_t)(pbase + bl + i) * DIM + s * 32 + j * 4);

  float xsq[2];
#pragma unroll
  for (int i = 0; i < 2; ++i) {
    float q = 0.f;
#pragma unroll
    for (int j = 0; j < 8; ++j)
      q += xv[i][j].x * xv[i][j].x + xv[i][j].y * xv[i][j].y +
           xv[i][j].z * xv[i][j].z + xv[i][j].w * xv[i][j].w;
    xsq[i] = q;
  }

  float acc[2][NC];
#pragma unroll
  for (int i = 0; i < 2; ++i)
#pragma unroll
    for (int c = 0; c < NC; ++c) acc[i][c] = 0.f;

#pragma unroll
  for (int c = 0; c < NC; ++c)
#pragma unroll
    for (int j = 0; j < 8; ++j) {
      float4 cv = cc[c * 64 + s * 8 + (j ^ s)];
#pragma unroll
      for (int i = 0; i < 2; ++i)
        acc[i][c] += xv[i][j].x * cv.x + xv[i][j].y * cv.y +
                     xv[i][j].z * cv.z + xv[i][j].w * cv.w;
    }

#pragma unroll
  for (int i = 0; i < 2; ++i) {
    xsq[i] += __shfl_xor(xsq[i], 1);
    xsq[i] += __shfl_xor(xsq[i], 2);
    xsq[i] += __shfl_xor(xsq[i], 4);
#pragma unroll
    for (int c = 0; c < NC; ++c) {
      acc[i][c] += __shfl_xor(acc[i][c], 1);
      acc[i][c] += __shfl_xor(acc[i][c], 2);
      acc[i][c] += __shfl_xor(acc[i][c], 4);
    }
  }

  switch (s) {
    ST_CASE(0) ST_CASE(1) ST_CASE(2) ST_CASE(3)
    ST_CASE(4) ST_CASE(5) ST_CASE(6) ST_CASE(7)
  }
}

// Radix-select; bin location via wave-0 hierarchical find (no block scans).
__global__ void __launch_bounds__(512) k_select(const float* __restrict__ Dmat,
                                                const int* __restrict__ gcounts,
                                                const int* __restrict__ offsets,
                                                float* __restrict__ pos_stat,
                                                float* __restrict__ neg_stat) {
  __shared__ unsigned int keys[VMAX];
  __shared__ int hist[2048];
  __shared__ int bsel[2];
  __shared__ float wsumf[8];
  __shared__ int wsumi[8];
  int tid = threadIdx.x;
  int lane = tid & 63, wv = tid >> 6;
  int b = blockIdx.x;
  int ci = b >> 4, cl = b & 15;
  bool largest = (ci == cl);
  int cnt = gcounts[cl];
  if (cnt > VMAX) cnt = VMAX;
  int off = offsets[cl];
  const float* src = Dmat + (size_t)ci * NPTS + off;
  unsigned int inv = largest ? 0xFFFFFFFFu : 0u;
  for (int t = tid; t < cnt; t += 512) keys[t] = __float_as_uint(src[t]) ^ inv;
  __syncthreads();

  int target = KSEL;
  unsigned int pfx = 0;

  // ---- Level A: bits [21,32), 2048 bins ----
  for (int u = tid; u < 2048; u += 512) hist[u] = 0;
  __syncthreads();
  for (int t = tid; t < cnt; t += 512) atomicAdd(&hist[keys[t] >> 21], 1);
  __syncthreads();
  if (tid < 64) {
    int own = 0;
#pragma unroll
    for (int j = 0; j < 32; ++j) own += hist[lane * 32 + j];
    int incl = own;
    for (int o = 1; o < 64; o <<= 1) { int n = __shfl_up(incl, o); if (lane >= o) incl += n; }
    int excl = incl - own;
    unsigned long long mk = __ballot(excl < target && target <= incl);
    int sel = __ffsll((unsigned long long)mk) - 1;
    if (lane == sel) {
      int run = excl;
      for (int j = 0; j < 32; ++j) {
        int h = hist[lane * 32 + j];
        if (run < target && target <= run + h) { bsel[0] = lane * 32 + j; bsel[1] = target - run; }
        run += h;
      }
    }
  }
  __syncthreads();
  pfx = ((unsigned int)bsel[0]) << 21; target = bsel[1];
  __syncthreads();

  // ---- Level B: bits [10,21), 2048 bins ----
  for (int u = tid; u < 2048; u += 512) hist[u] = 0;
  __syncthreads();
  for (int t = tid; t < cnt; t += 512) {
    unsigned int k = keys[t];
    if ((k >> 21) == (pfx >> 21)) atomicAdd(&hist[(k >> 10) & 0x7FF], 1);
  }
  __syncthreads();
  if (tid < 64) {
    int own = 0;
#pragma unroll
    for (int j = 0; j < 32; ++j) own += hist[lane * 32 + j];
    int incl = own;
    for (int o = 1; o < 64; o <<= 1) { int n = __shfl_up(incl, o); if (lane >= o) incl += n; }
    int excl = incl - own;
    unsigned long long mk = __ballot(excl < target && target <= incl);
    int sel = __ffsll((unsigned long long)mk) - 1;
    if (lane == sel) {
      int run = excl;
      for (int j = 0; j < 32; ++j) {
        int h = hist[lane * 32 + j];
        if (run < target && target <= run + h) { bsel[0] = lane * 32 + j; bsel[1] = target - run; }
        run += h;
      }
    }
  }
  __syncthreads();
  pfx |= ((unsigned int)bsel[0]) << 10; target = bsel[1];
  __syncthreads();

  // ---- Level C: bits [0,10), 1024 bins ----
  for (int u = tid; u < 1024; u += 512) hist[u] = 0;
  __syncthreads();
  for (int t = tid; t < cnt; t += 512) {
    unsigned int k = keys[t];
    if ((k >> 10) == (pfx >> 10)) atomicAdd(&hist[k & 0x3FF], 1);
  }
  __syncthreads();
  if (tid < 64) {
    int own = 0;
#pragma unroll
    for (int j = 0; j < 16; ++j) own += hist[lane * 16 + j];
    int incl = own;
    for (int o = 1; o < 64; o <<= 1) { int n = __shfl_up(incl, o); if (lane >= o) incl += n; }
    int excl = incl - own;
    unsigned long long mk = __ballot(excl < target && target <= incl);
    int sel = __ffsll((unsigned long long)mk) - 1;
    if (lane == sel) {
      int run = excl;
      for (int j = 0; j < 16; ++j) {
        int h = hist[lane * 16 + j];
        if (run < target && target <= run + h) { bsel[0] = lane * 16 + j; }
        run += h;
      }
    }
  }
  __syncthreads();
  unsigned int T = pfx | (unsigned int)bsel[0];
  float fT = __uint_as_float(T ^ inv);

  // ---- pass 1: n_less, sum_less (wave reduce + 8-entry combine) ----
  int nl = 0; float sl = 0.f;
  for (int t = tid; t < cnt; t += 512) {
    unsigned int k = keys[t];
    if (k < T) { nl++; sl += __uint_as_float(k ^ inv); }
  }
#pragma unroll
  for (int m = 1; m < 64; m <<= 1) { nl += __shfl_xor(nl, m); sl += __shfl_xor(sl, m); }
  if (lane == 0) { wsumi[wv] = nl; wsumf[wv] = sl; }
  __syncthreads();
  int n_less = 0; float s_less = 0.f;
#pragma unroll
  for (int w2 = 0; w2 < 8; ++w2) { n_less += wsumi[w2]; s_less += wsumf[w2]; }
  float mean = (s_less + (float)(KSEL - n_less) * fT) / (float)KSEL;
  __syncthreads();

  // ---- pass 2: variance ----
  float sv = 0.f;
  for (int t = tid; t < cnt; t += 512) {
    unsigned int k = keys[t];
    if (k < T) { float d = __uint_as_float(k ^ inv) - mean; sv += d * d; }
  }
#pragma unroll
  for (int m = 1; m < 64; m <<= 1) sv += __shfl_xor(sv, m);
  if (lane == 0) wsumf[wv] = sv;
  __syncthreads();
  if (tid == 0) {
    float vs = 0.f;
#pragma unroll
    for (int w2 = 0; w2 < 8; ++w2) vs += wsumf[w2];
    float dT = fT - mean;
    float var = (vs + (float)(KSEL - n_less) * dT * dT) / (float)(KSEL - 1);
    if (largest) pos_stat[ci] = mean + 1.96f * sqrtf(var);
    else neg_stat[ci * 16 + cl] = mean - 1.96f * sqrtf(var);
  }
}

__global__ void __launch_bounds__(256) k_loss(const float* __restrict__ pos_stat,
                                              const float* __restrict__ neg_stat,
                                              float* __restrict__ out) {
  __shared__ float red[256];
  int t = threadIdx.x;
  int i = t >> 4, c = t & 15;
  float v = 0.f;
  if (i != c) v = fmaxf(1.0f + pos_stat[i] - neg_stat[t], 0.f);
  red[t] = v; __syncthreads();
  for (int st = 128; st > 0; st >>= 1) { if (t < st) red[t] += red[t + st]; __syncthreads(); }
  if (t == 0) out[0] = red[0];
}

extern "C" void kernel_launch(void* const* d_in, const int* in_sizes, int n_in,
                              void* d_out, int out_size, void* d_ws, size_t ws_size,
                              hipStream_t stream) {
  const float* x = (const float*)d_in[0];
  const int* y = (const int*)d_in[1];
  float* out = (float*)d_out;
  char* ws = (char*)d_ws;

  float* sums = (float*)(ws + 0);
  int* counts = (int*)(ws + 16384);
  int* offsets = (int*)(ws + 16512);
  float* csq = (float*)(ws + 16576);
  float* pos_stat = (float*)(ws + 16640);
  float* neg_stat = (float*)(ws + 16704);
  float* centers = (float*)(ws + 17728);
  int* bhist = (int*)(ws + 34112);
  float* Dmat = (float*)(ws + 65536);
  float* partials = (float*)(ws + 65536);   // [1024][4096] = 16 MB, consumed pre-k_dist
  int* slots = (int*)(ws + 16842752);

  k_hist<<<256, 256, 0, stream>>>(y, bhist);
  k_scan<<<1, 256, 0, stream>>>(bhist, counts, offsets, sums);
  k_slot<<<256, 256, 0, stream>>>(y, bhist, slots);
  k_accum<<<1024, 256, 0, stream>>>(x, y, partials);
  k_reduce<<<128, 256, 0, stream>>>(partials, sums);
  k_centers<<<16, 256, 0, stream>>>(sums, counts, centers, csq);
  k_dist<<<1024, 256, 0, stream>>>(x, centers, csq, slots, Dmat);
  k_select<<<256, 512, 0, stream>>>(Dmat, counts, offsets, pos_stat, neg_stat);
  k_loss<<<1, 256, 0, stream>>>(pos_stat, neg_stat, out);
}

// Round 21
// 80.824 us; speedup vs baseline: 2.3318x; 1.1387x over previous
//
#include <hip/hip_runtime.h>
#include <cfloat>
#include <cstdint>

#define NPTS 65536
#define DIM 256
#define NC 16
#define KSEL 2048
#define VMAX 4608
#define EPSV 1e-6f

typedef __attribute__((ext_vector_type(8))) short short8v;
typedef __attribute__((ext_vector_type(4))) float f32x4;

// ws layout (bytes):
//     0 : float sums[16*256]   (16384)
// 16384 : int counts[16]       (64)
// 16512 : int offsets[16]      (64)
// 16576 : float csq[16]        (64)
// 16640 : float pos_stat[16]   (64)
// 16704 : float neg_stat[256]  (1024)
// 17728 : float centers[4096]  (16384)
// 34112 : int bhist[256*16]    (16384)
// 50688 : ushort cfb[4096]     (8192)   -- centers in bf16 MFMA A-fragment order
// 65536 : float Dmat[16*65536] (4 MB) -- also start of partials[1024][4096] (16 MB) pre-k_dist
// 16842752 : int slots[65536]  (256 KB)

__global__ void __launch_bounds__(256) k_hist(const int* __restrict__ y,
                                              int* __restrict__ bhist) {
  __shared__ int h[NC];
  int t = threadIdx.x;
  if (t < NC) h[t] = 0;
  __syncthreads();
  int p = blockIdx.x * 256 + t;
  atomicAdd(&h[y[p * 3 + 2]], 1);
  __syncthreads();
  if (t < NC) bhist[blockIdx.x * NC + t] = h[t];
}

// Scan bhist per class across 256 chunks; emits counts/offsets; zeroes gsums.
__global__ void __launch_bounds__(256) k_scan(int* __restrict__ bhist,
                                              int* __restrict__ counts,
                                              int* __restrict__ offsets,
                                              float* __restrict__ gsums) {
  __shared__ int lh[256 * NC];
  __shared__ int segbase[16][NC];
  __shared__ int totl[NC], offl[NC];
  int t = threadIdx.x;
  for (int u = t; u < NC * DIM; u += 256) gsums[u] = 0.f;
  for (int u = t; u < 256 * NC; u += 256) lh[u] = bhist[u];
  __syncthreads();
  int c = t & 15, g = t >> 4;
  int part = 0;
#pragma unroll
  for (int b = 0; b < 16; ++b) part += lh[(g * 16 + b) * NC + c];
  segbase[g][c] = part;
  __syncthreads();
  if (t < NC) {
    int tot = 0;
#pragma unroll
    for (int g2 = 0; g2 < 16; ++g2) tot += segbase[g2][t];
    totl[t] = tot;
    counts[t] = tot;
  }
  __syncthreads();
  if (t == 0) {
    int run = 0;
    for (int c2 = 0; c2 < NC; ++c2) { offl[c2] = run; offsets[c2] = run; run += totl[c2]; }
  }
  __syncthreads();
  if (t < NC) {
    int run = offl[t];
#pragma unroll
    for (int g2 = 0; g2 < 16; ++g2) { int tmp = segbase[g2][t]; segbase[g2][t] = run; run += tmp; }
  }
  __syncthreads();
  int run = segbase[g][c];
#pragma unroll
  for (int b = 0; b < 16; ++b) {
    int idx = (g * 16 + b) * NC + c;
    int tmp = lh[idx]; lh[idx] = run; run += tmp;
  }
  __syncthreads();
  for (int u = t; u < 256 * NC; u += 256) bhist[u] = lh[u];
}

// slot[p] = chunk base + stable rank, rank via 16 ballots (no serial loop).
__global__ void __launch_bounds__(256) k_slot(const int* __restrict__ y,
                                              const int* __restrict__ bbase,
                                              int* __restrict__ slots) {
  __shared__ int labs[256];
  __shared__ int wcnt[4][NC];
  int t = threadIdx.x;
  int chunk = blockIdx.x;
  labs[t] = y[(chunk * 256 + t) * 3 + 2];
  __syncthreads();
  int lab = labs[t];
  int lane = t & 63, w = t >> 6;
  unsigned long long mymask = 0;
#pragma unroll
  for (int c = 0; c < NC; ++c) {
    unsigned long long mk = __ballot(lab == c);
    if (lane == 0) wcnt[w][c] = __popcll(mk);
    if (lab == c) mymask = mk;
  }
  __syncthreads();
  int rank = __popcll(mymask & ((1ull << lane) - 1ull));
  for (int w2 = 0; w2 < w; ++w2) rank += wcnt[w2][lab];
  slots[chunk * 256 + t] = bbase[chunk * NC + lab] + rank;
}

#define ACC_CASE(C) case C: acc[C][0] += xv[u].x; acc[C][1] += xv[u].y; \
                            acc[C][2] += xv[u].z; acc[C][3] += xv[u].w; break;

// 1024 blocks x 64 rows; wave w owns rows [16w,16w+16). 32KB two-phase LDS
// combine. No min-waves bound (R17: (256,4) clamped VGPR->64, spilled acc).
__global__ void __launch_bounds__(256) k_accum(const float* __restrict__ x,
                                               const int* __restrict__ y,
                                               float* __restrict__ partials) {
  __shared__ int labs[64];
  __shared__ float red[2 * NC * DIM];  // 32 KB
  int t = threadIdx.x;
  int n0 = blockIdx.x * 64;
  if (t < 64) labs[t] = y[(n0 + t) * 3 + 2];
  __syncthreads();
  int w = t >> 6, m = t & 63;

  float acc[NC][4];
#pragma unroll
  for (int c = 0; c < NC; ++c)
#pragma unroll
    for (int j = 0; j < 4; ++j) acc[c][j] = 0.f;

  for (int r0 = 0; r0 < 16; r0 += 4) {
    float4 xv[4];
#pragma unroll
    for (int u = 0; u < 4; ++u)
      xv[u] = *(const float4*)(x + (size_t)(n0 + 16 * w + r0 + u) * DIM + 4 * m);
#pragma unroll
    for (int u = 0; u < 4; ++u) {
      int lab = __builtin_amdgcn_readfirstlane(labs[16 * w + r0 + u]);
      switch (lab) {
        ACC_CASE(0) ACC_CASE(1) ACC_CASE(2) ACC_CASE(3)
        ACC_CASE(4) ACC_CASE(5) ACC_CASE(6) ACC_CASE(7)
        ACC_CASE(8) ACC_CASE(9) ACC_CASE(10) ACC_CASE(11)
        ACC_CASE(12) ACC_CASE(13) ACC_CASE(14) ACC_CASE(15)
      }
    }
  }

  int half = w & 1;
  if (w < 2) {
#pragma unroll
    for (int c = 0; c < NC; ++c)
#pragma unroll
      for (int j = 0; j < 4; ++j)
        red[half * (NC * DIM) + c * DIM + 4 * m + j] = acc[c][j];
  }
  __syncthreads();
  if (w >= 2) {
#pragma unroll
    for (int c = 0; c < NC; ++c)
#pragma unroll
      for (int j = 0; j < 4; ++j)
        red[half * (NC * DIM) + c * DIM + 4 * m + j] += acc[c][j];
  }
  __syncthreads();
  for (int u = t; u < NC * DIM; u += 256)
    partials[(size_t)blockIdx.x * (NC * DIM) + u] = red[u] + red[NC * DIM + u];
}

// 8 slices x 128 chunks each over 1024 partials; combined via atomicAdd.
__global__ void __launch_bounds__(256) k_reduce(const float* __restrict__ partials,
                                                float* __restrict__ gsums) {
  int tg = blockIdx.x * 256 + threadIdx.x;
  int u = tg & 4095;
  int s = tg >> 12;
  float acc = 0.f;
#pragma unroll 8
  for (int b = s * 128; b < s * 128 + 128; ++b)
    acc += partials[(size_t)b * (NC * DIM) + u];
  atomicAdd(&gsums[u], acc);
}

// 16 blocks (one class each): centers + csq + bf16 A-fragment table cfb.
// cfb layout: for consuming lane l, kc: cfb[kc*512 + l*8 + j] =
// bf16(centers[m=l&15][kc*32 + (l>>4)*8 + j]). Block c covers l&15==c.
__global__ void __launch_bounds__(256) k_centers(const float* __restrict__ gsums,
                                                 const int* __restrict__ gcounts,
                                                 float* __restrict__ centers,
                                                 float* __restrict__ csq,
                                                 unsigned short* __restrict__ cfb) {
  __shared__ float wsum[4];
  int d = threadIdx.x, c = blockIdx.x;
  float v = gsums[c * DIM + d] / (float)gcounts[c] + EPSV;
  centers[c * DIM + d] = v;
  // bf16 (RNE) into fragment order
  unsigned int bits = __float_as_uint(v);
  unsigned short h = (unsigned short)((bits + 0x7FFFu + ((bits >> 16) & 1u)) >> 16);
  int kc = d >> 5, lg = (d >> 3) & 3, j = d & 7;
  int l = lg * 16 + c;
  cfb[kc * 512 + l * 8 + j] = h;
  float q = v * v;
#pragma unroll
  for (int m = 1; m < 64; m <<= 1) q += __shfl_xor(q, m);
  if ((d & 63) == 0) wsum[d >> 6] = q;
  __syncthreads();
  if (d == 0) csq[c] = wsum[0] + wsum[1] + wsum[2] + wsum[3];
}

__device__ __forceinline__ unsigned int cvt_pk_bf16(float lo, float hi) {
  unsigned int r;
  asm("v_cvt_pk_bf16_f32 %0, %1, %2" : "=v"(r) : "v"(lo), "v"(hi));
  return r;
}

// MFMA k_dist: D = centers(bf16) . x(bf16), xsq in fp32. No LDS inner loop.
// Wave = 16 points; lane l: point p=l&15, K-slice (l>>4)*8+j per 32-dim chunk.
// acc[j] = c.x for center m=(l>>4)*4+j, point l&15 (verified C/D layout).
__global__ void __launch_bounds__(256) k_dist(const float* __restrict__ x,
                                              const unsigned short* __restrict__ cfb,
                                              const float* __restrict__ csq,
                                              const int* __restrict__ slots,
                                              float* __restrict__ Dmat) {
  __shared__ float csql[NC];
  __shared__ int slotL[64];
  int t = threadIdx.x;
  if (t < NC) csql[t] = csq[t];
  int pbase = blockIdx.x * 64;
  if (t < 64) slotL[t] = slots[pbase + t];
  __syncthreads();

  int wave = t >> 6, l = t & 63;
  int lg = l >> 4;                 // 0..3 (K-group)
  int pl = wave * 16 + (l & 15);   // local point
  int p = pbase + pl;

  const float4* xrow = (const float4*)(x + (size_t)p * DIM);
  float4 xa[8][2];
#pragma unroll
  for (int kc = 0; kc < 8; ++kc) {
    xa[kc][0] = xrow[kc * 8 + lg * 2 + 0];
    xa[kc][1] = xrow[kc * 8 + lg * 2 + 1];
  }

  float xsq = 0.f;
#pragma unroll
  for (int kc = 0; kc < 8; ++kc) {
    float4 a0 = xa[kc][0], a1 = xa[kc][1];
    xsq += a0.x * a0.x + a0.y * a0.y + a0.z * a0.z + a0.w * a0.w +
           a1.x * a1.x + a1.y * a1.y + a1.z * a1.z + a1.w * a1.w;
  }
  // combine the 4 K-groups of this point (lanes l, l^16, l^32, l^48)
  xsq += __shfl_xor(xsq, 16);
  xsq += __shfl_xor(xsq, 32);

  const uint4* cfp = (const uint4*)cfb;
  f32x4 acc = {0.f, 0.f, 0.f, 0.f};
#pragma unroll
  for (int kc = 0; kc < 8; ++kc) {
    union { unsigned int u[4]; short8v s; } xb, cf;
    float4 a0 = xa[kc][0], a1 = xa[kc][1];
    xb.u[0] = cvt_pk_bf16(a0.x, a0.y);
    xb.u[1] = cvt_pk_bf16(a0.z, a0.w);
    xb.u[2] = cvt_pk_bf16(a1.x, a1.y);
    xb.u[3] = cvt_pk_bf16(a1.z, a1.w);
    uint4 cw = cfp[kc * 64 + l];
    cf.u[0] = cw.x; cf.u[1] = cw.y; cf.u[2] = cw.z; cf.u[3] = cw.w;
    acc = __builtin_amdgcn_mfma_f32_16x16x32_bf16(cf.s, xb.s, acc, 0, 0, 0);
  }

  int slot = slotL[pl];
#pragma unroll
  for (int j = 0; j < 4; ++j) {
    int m = lg * 4 + j;
    float d2 = csql[m] - 2.f * acc[j] + xsq;
    Dmat[(size_t)m * NPTS + slot] = sqrtf(fmaxf(d2, 0.f));
  }
}

// Radix-select; bin location via wave-0 hierarchical find (no block scans).
__global__ void __launch_bounds__(512) k_select(const float* __restrict__ Dmat,
                                                const int* __restrict__ gcounts,
                                                const int* __restrict__ offsets,
                                                float* __restrict__ pos_stat,
                                                float* __restrict__ neg_stat) {
  __shared__ unsigned int keys[VMAX];
  __shared__ int hist[2048];
  __shared__ int bsel[2];
  __shared__ float wsumf[8];
  __shared__ int wsumi[8];
  int tid = threadIdx.x;
  int lane = tid & 63, wv = tid >> 6;
  int b = blockIdx.x;
  int ci = b >> 4, cl = b & 15;
  bool largest = (ci == cl);
  int cnt = gcounts[cl];
  if (cnt > VMAX) cnt = VMAX;
  int off = offsets[cl];
  const float* src = Dmat + (size_t)ci * NPTS + off;
  unsigned int inv = largest ? 0xFFFFFFFFu : 0u;
  for (int t = tid; t < cnt; t += 512) keys[t] = __float_as_uint(src[t]) ^ inv;
  __syncthreads();

  int target = KSEL;
  unsigned int pfx = 0;

  for (int u = tid; u < 2048; u += 512) hist[u] = 0;
  __syncthreads();
  for (int t = tid; t < cnt; t += 512) atomicAdd(&hist[keys[t] >> 21], 1);
  __syncthreads();
  if (tid < 64) {
    int own = 0;
#pragma unroll
    for (int j = 0; j < 32; ++j) own += hist[lane * 32 + j];
    int incl = own;
    for (int o = 1; o < 64; o <<= 1) { int n = __shfl_up(incl, o); if (lane >= o) incl += n; }
    int excl = incl - own;
    unsigned long long mk = __ballot(excl < target && target <= incl);
    int sel = __ffsll((unsigned long long)mk) - 1;
    if (lane == sel) {
      int run = excl;
      for (int j = 0; j < 32; ++j) {
        int h = hist[lane * 32 + j];
        if (run < target && target <= run + h) { bsel[0] = lane * 32 + j; bsel[1] = target - run; }
        run += h;
      }
    }
  }
  __syncthreads();
  pfx = ((unsigned int)bsel[0]) << 21; target = bsel[1];
  __syncthreads();

  for (int u = tid; u < 2048; u += 512) hist[u] = 0;
  __syncthreads();
  for (int t = tid; t < cnt; t += 512) {
    unsigned int k = keys[t];
    if ((k >> 21) == (pfx >> 21)) atomicAdd(&hist[(k >> 10) & 0x7FF], 1);
  }
  __syncthreads();
  if (tid < 64) {
    int own = 0;
#pragma unroll
    for (int j = 0; j < 32; ++j) own += hist[lane * 32 + j];
    int incl = own;
    for (int o = 1; o < 64; o <<= 1) { int n = __shfl_up(incl, o); if (lane >= o) incl += n; }
    int excl = incl - own;
    unsigned long long mk = __ballot(excl < target && target <= incl);
    int sel = __ffsll((unsigned long long)mk) - 1;
    if (lane == sel) {
      int run = excl;
      for (int j = 0; j < 32; ++j) {
        int h = hist[lane * 32 + j];
        if (run < target && target <= run + h) { bsel[0] = lane * 32 + j; bsel[1] = target - run; }
        run += h;
      }
    }
  }
  __syncthreads();
  pfx |= ((unsigned int)bsel[0]) << 10; target = bsel[1];
  __syncthreads();

  for (int u = tid; u < 1024; u += 512) hist[u] = 0;
  __syncthreads();
  for (int t = tid; t < cnt; t += 512) {
    unsigned int k = keys[t];
    if ((k >> 10) == (pfx >> 10)) atomicAdd(&hist[k & 0x3FF], 1);
  }
  __syncthreads();
  if (tid < 64) {
    int own = 0;
#pragma unroll
    for (int j = 0; j < 16; ++j) own += hist[lane * 16 + j];
    int incl = own;
    for (int o = 1; o < 64; o <<= 1) { int n = __shfl_up(incl, o); if (lane >= o) incl += n; }
    int excl = incl - own;
    unsigned long long mk = __ballot(excl < target && target <= incl);
    int sel = __ffsll((unsigned long long)mk) - 1;
    if (lane == sel) {
      int run = excl;
      for (int j = 0; j < 16; ++j) {
        int h = hist[lane * 16 + j];
        if (run < target && target <= run + h) { bsel[0] = lane * 16 + j; }
        run += h;
      }
    }
  }
  __syncthreads();
  unsigned int T = pfx | (unsigned int)bsel[0];
  float fT = __uint_as_float(T ^ inv);

  int nl = 0; float sl = 0.f;
  for (int t = tid; t < cnt; t += 512) {
    unsigned int k = keys[t];
    if (k < T) { nl++; sl += __uint_as_float(k ^ inv); }
  }
#pragma unroll
  for (int m = 1; m < 64; m <<= 1) { nl += __shfl_xor(nl, m); sl += __shfl_xor(sl, m); }
  if (lane == 0) { wsumi[wv] = nl; wsumf[wv] = sl; }
  __syncthreads();
  int n_less = 0; float s_less = 0.f;
#pragma unroll
  for (int w2 = 0; w2 < 8; ++w2) { n_less += wsumi[w2]; s_less += wsumf[w2]; }
  float mean = (s_less + (float)(KSEL - n_less) * fT) / (float)KSEL;
  __syncthreads();

  float sv = 0.f;
  for (int t = tid; t < cnt; t += 512) {
    unsigned int k = keys[t];
    if (k < T) { float d = __uint_as_float(k ^ inv) - mean; sv += d * d; }
  }
#pragma unroll
  for (int m = 1; m < 64; m <<= 1) sv += __shfl_xor(sv, m);
  if (lane == 0) wsumf[wv] = sv;
  __syncthreads();
  if (tid == 0) {
    float vs = 0.f;
#pragma unroll
    for (int w2 = 0; w2 < 8; ++w2) vs += wsumf[w2];
    float dT = fT - mean;
    float var = (vs + (float)(KSEL - n_less) * dT * dT) / (float)(KSEL - 1);
    if (largest) pos_stat[ci] = mean + 1.96f * sqrtf(var);
    else neg_stat[ci * 16 + cl] = mean - 1.96f * sqrtf(var);
  }
}

__global__ void __launch_bounds__(256) k_loss(const float* __restrict__ pos_stat,
                                              const float* __restrict__ neg_stat,
                                              float* __restrict__ out) {
  __shared__ float red[256];
  int t = threadIdx.x;
  int i = t >> 4, c = t & 15;
  float v = 0.f;
  if (i != c) v = fmaxf(1.0f + pos_stat[i] - neg_stat[t], 0.f);
  red[t] = v; __syncthreads();
  for (int st = 128; st > 0; st >>= 1) { if (t < st) red[t] += red[t + st]; __syncthreads(); }
  if (t == 0) out[0] = red[0];
}

extern "C" void kernel_launch(void* const* d_in, const int* in_sizes, int n_in,
                              void* d_out, int out_size, void* d_ws, size_t ws_size,
                              hipStream_t stream) {
  const float* x = (const float*)d_in[0];
  const int* y = (const int*)d_in[1];
  float* out = (float*)d_out;
  char* ws = (char*)d_ws;

  float* sums = (float*)(ws + 0);
  int* counts = (int*)(ws + 16384);
  int* offsets = (int*)(ws + 16512);
  float* csq = (float*)(ws + 16576);
  float* pos_stat = (float*)(ws + 16640);
  float* neg_stat = (float*)(ws + 16704);
  float* centers = (float*)(ws + 17728);
  int* bhist = (int*)(ws + 34112);
  unsigned short* cfb = (unsigned short*)(ws + 50688);
  float* Dmat = (float*)(ws + 65536);
  float* partials = (float*)(ws + 65536);   // [1024][4096] = 16 MB, consumed pre-k_dist
  int* slots = (int*)(ws + 16842752);

  k_hist<<<256, 256, 0, stream>>>(y, bhist);
  k_scan<<<1, 256, 0, stream>>>(bhist, counts, offsets, sums);
  k_slot<<<256, 256, 0, stream>>>(y, bhist, slots);
  k_accum<<<1024, 256, 0, stream>>>(x, y, partials);
  k_reduce<<<128, 256, 0, stream>>>(partials, sums);
  k_centers<<<16, 256, 0, stream>>>(sums, counts, centers, csq, cfb);
  k_dist<<<1024, 256, 0, stream>>>(x, cfb, csq, slots, Dmat);
  k_select<<<256, 512, 0, stream>>>(Dmat, counts, offsets, pos_stat, neg_stat);
  k_loss<<<1, 256, 0, stream>>>(pos_stat, neg_stat, out);
}

// Round 22
// 72.146 us; speedup vs baseline: 2.6123x; 1.1203x over previous
//
#include <hip/hip_runtime.h>
#include <cfloat>
#include <cstdint>

#define NPTS 65536
#define DIM 256
#define NC 16
#define KSEL 2048
#define VMAX 4608
#define EPSV 1e-6f

typedef __attribute__((ext_vector_type(8))) short short8v;
typedef __attribute__((ext_vector_type(4))) float f32x4;

// ws layout (bytes):
// 16384 : int counts[16]       (64)
// 16512 : int offsets[16]      (64)
// 16576 : float csq[16]        (64)
// 16640 : float pos_stat[16]   (64)
// 16704 : float neg_stat[256]  (1024)
// 17728 : float centers[4096]  (16384)
// 34112 : int bhist[256*16]    (16384)
// 50688 : ushort cfb[4096]     (8192)   -- centers in bf16 MFMA A-fragment order
// 65536 : float Dmat[16*65536] (4 MB) -- also partials[512][4096] (8 MB) pre-k_dist
// 16842752 : int slots[65536]  (256 KB)  packed (lab<<16 | rank)
// 33554432 : float partial2[8*4096] (128 KB)

// Merged hist+rank: ballot-rank gives per-wave class counts; hist falls out.
__global__ void __launch_bounds__(256) k_histrank(const int* __restrict__ y,
                                                  int* __restrict__ bhist,
                                                  int* __restrict__ slots) {
  __shared__ int labs[256];
  __shared__ int wcnt[4][NC];
  int t = threadIdx.x;
  int chunk = blockIdx.x;
  labs[t] = y[(chunk * 256 + t) * 3 + 2];
  __syncthreads();
  int lab = labs[t];
  int lane = t & 63, w = t >> 6;
  unsigned long long mymask = 0;
#pragma unroll
  for (int c = 0; c < NC; ++c) {
    unsigned long long mk = __ballot(lab == c);
    if (lane == 0) wcnt[w][c] = __popcll(mk);
    if (lab == c) mymask = mk;
  }
  __syncthreads();
  int rank = __popcll(mymask & ((1ull << lane) - 1ull));
  for (int w2 = 0; w2 < w; ++w2) rank += wcnt[w2][lab];
  slots[chunk * 256 + t] = (lab << 16) | rank;
  if (t < NC) bhist[chunk * NC + t] = wcnt[0][t] + wcnt[1][t] + wcnt[2][t] + wcnt[3][t];
}

// Scan bhist per class across 256 chunks; emits counts/offsets.
__global__ void __launch_bounds__(256) k_scan(int* __restrict__ bhist,
                                              int* __restrict__ counts,
                                              int* __restrict__ offsets) {
  __shared__ int lh[256 * NC];
  __shared__ int segbase[16][NC];
  __shared__ int totl[NC], offl[NC];
  int t = threadIdx.x;
  for (int u = t; u < 256 * NC; u += 256) lh[u] = bhist[u];
  __syncthreads();
  int c = t & 15, g = t >> 4;
  int part = 0;
#pragma unroll
  for (int b = 0; b < 16; ++b) part += lh[(g * 16 + b) * NC + c];
  segbase[g][c] = part;
  __syncthreads();
  if (t < NC) {
    int tot = 0;
#pragma unroll
    for (int g2 = 0; g2 < 16; ++g2) tot += segbase[g2][t];
    totl[t] = tot;
    counts[t] = tot;
  }
  __syncthreads();
  if (t == 0) {
    int run = 0;
    for (int c2 = 0; c2 < NC; ++c2) { offl[c2] = run; offsets[c2] = run; run += totl[c2]; }
  }
  __syncthreads();
  if (t < NC) {
    int run = offl[t];
#pragma unroll
    for (int g2 = 0; g2 < 16; ++g2) { int tmp = segbase[g2][t]; segbase[g2][t] = run; run += tmp; }
  }
  __syncthreads();
  int run = segbase[g][c];
#pragma unroll
  for (int b = 0; b < 16; ++b) {
    int idx = (g * 16 + b) * NC + c;
    int tmp = lh[idx]; lh[idx] = run; run += tmp;
  }
  __syncthreads();
  for (int u = t; u < 256 * NC; u += 256) bhist[u] = lh[u];
}

#define ACC_CASE(C) case C: acc[C][0] += xv[u].x; acc[C][1] += xv[u].y; \
                            acc[C][2] += xv[u].z; acc[C][3] += xv[u].w; break;

// 512 blocks x 128 rows; wave w owns rows [32w,32w+32). 32KB two-phase LDS
// combine. No min-waves bound (R17: (256,4) clamped VGPR->64, spilled acc).
__global__ void __launch_bounds__(256) k_accum(const float* __restrict__ x,
                                               const int* __restrict__ y,
                                               float* __restrict__ partials) {
  __shared__ int labs[128];
  __shared__ float red[2 * NC * DIM];  // 32 KB
  int t = threadIdx.x;
  int n0 = blockIdx.x * 128;
  if (t < 128) labs[t] = y[(n0 + t) * 3 + 2];
  __syncthreads();
  int w = t >> 6, m = t & 63;

  float acc[NC][4];
#pragma unroll
  for (int c = 0; c < NC; ++c)
#pragma unroll
    for (int j = 0; j < 4; ++j) acc[c][j] = 0.f;

  for (int r0 = 0; r0 < 32; r0 += 4) {
    float4 xv[4];
#pragma unroll
    for (int u = 0; u < 4; ++u)
      xv[u] = *(const float4*)(x + (size_t)(n0 + 32 * w + r0 + u) * DIM + 4 * m);
#pragma unroll
    for (int u = 0; u < 4; ++u) {
      int lab = __builtin_amdgcn_readfirstlane(labs[32 * w + r0 + u]);
      switch (lab) {
        ACC_CASE(0) ACC_CASE(1) ACC_CASE(2) ACC_CASE(3)
        ACC_CASE(4) ACC_CASE(5) ACC_CASE(6) ACC_CASE(7)
        ACC_CASE(8) ACC_CASE(9) ACC_CASE(10) ACC_CASE(11)
        ACC_CASE(12) ACC_CASE(13) ACC_CASE(14) ACC_CASE(15)
      }
    }
  }

  int half = w & 1;
  if (w < 2) {
#pragma unroll
    for (int c = 0; c < NC; ++c)
#pragma unroll
      for (int j = 0; j < 4; ++j)
        red[half * (NC * DIM) + c * DIM + 4 * m + j] = acc[c][j];
  }
  __syncthreads();
  if (w >= 2) {
#pragma unroll
    for (int c = 0; c < NC; ++c)
#pragma unroll
      for (int j = 0; j < 4; ++j)
        red[half * (NC * DIM) + c * DIM + 4 * m + j] += acc[c][j];
  }
  __syncthreads();
  for (int u = t; u < NC * DIM; u += 256)
    partials[(size_t)blockIdx.x * (NC * DIM) + u] = red[u] + red[NC * DIM + u];
}

// 8 slices x 64 chunks over 512 partials; plain stores (no atomics).
__global__ void __launch_bounds__(256) k_reduce(const float* __restrict__ partials,
                                                float* __restrict__ partial2) {
  int tg = blockIdx.x * 256 + threadIdx.x;  // 128 blocks -> 32768 = 8*4096
  int u = tg & 4095;
  int s = tg >> 12;
  float acc = 0.f;
#pragma unroll 8
  for (int b = s * 64; b < s * 64 + 64; ++b)
    acc += partials[(size_t)b * (NC * DIM) + u];
  partial2[s * 4096 + u] = acc;
}

// 16 blocks (one class each): sum 8 slices, centers + csq + cfb.
// cfb: for consuming lane l, kc: cfb[kc*512 + l*8 + j] =
// bf16(centers[m=l&15][kc*32 + (l>>4)*8 + j]). Block c covers l&15==c.
__global__ void __launch_bounds__(256) k_centers(const float* __restrict__ partial2,
                                                 const int* __restrict__ gcounts,
                                                 float* __restrict__ centers,
                                                 float* __restrict__ csq,
                                                 unsigned short* __restrict__ cfb) {
  __shared__ float wsum[4];
  int d = threadIdx.x, c = blockIdx.x;
  float v = 0.f;
#pragma unroll
  for (int s = 0; s < 8; ++s) v += partial2[s * 4096 + c * DIM + d];
  v = v / (float)gcounts[c] + EPSV;
  centers[c * DIM + d] = v;
  unsigned int bits = __float_as_uint(v);
  unsigned short h = (unsigned short)((bits + 0x7FFFu + ((bits >> 16) & 1u)) >> 16);
  int kc = d >> 5, lg = (d >> 3) & 3, j = d & 7;
  int l = lg * 16 + c;
  cfb[kc * 512 + l * 8 + j] = h;
  float q = v * v;
#pragma unroll
  for (int m = 1; m < 64; m <<= 1) q += __shfl_xor(q, m);
  if ((d & 63) == 0) wsum[d >> 6] = q;
  __syncthreads();
  if (d == 0) csq[c] = wsum[0] + wsum[1] + wsum[2] + wsum[3];
}

__device__ __forceinline__ unsigned int cvt_pk_bf16(float lo, float hi) {
  unsigned int r;
  asm("v_cvt_pk_bf16_f32 %0, %1, %2" : "=v"(r) : "v"(lo), "v"(hi));
  return r;
}

// MFMA k_dist: D = centers(bf16) . x(bf16), xsq fp32. Slot resolved from
// packed (lab<<16|rank) + per-chunk bhist base (chunk = blockIdx>>2).
__global__ void __launch_bounds__(256) k_dist(const float* __restrict__ x,
                                              const unsigned short* __restrict__ cfb,
                                              const float* __restrict__ csq,
                                              const int* __restrict__ slots,
                                              const int* __restrict__ bbase,
                                              float* __restrict__ Dmat) {
  __shared__ float csql[NC];
  __shared__ int baseL[NC];
  __shared__ int slotL[64];
  int t = threadIdx.x;
  if (t < NC) {
    csql[t] = csq[t];
    baseL[t] = bbase[(blockIdx.x >> 2) * NC + t];
  }
  __syncthreads();
  int pbase = blockIdx.x * 64;
  if (t < 64) {
    int sp = slots[pbase + t];
    slotL[t] = baseL[sp >> 16] + (sp & 0xFFFF);
  }
  __syncthreads();

  int wave = t >> 6, l = t & 63;
  int lg = l >> 4;                 // 0..3 (K-group)
  int pl = wave * 16 + (l & 15);   // local point
  int p = pbase + pl;

  const float4* xrow = (const float4*)(x + (size_t)p * DIM);
  float4 xa[8][2];
#pragma unroll
  for (int kc = 0; kc < 8; ++kc) {
    xa[kc][0] = xrow[kc * 8 + lg * 2 + 0];
    xa[kc][1] = xrow[kc * 8 + lg * 2 + 1];
  }

  float xsq = 0.f;
#pragma unroll
  for (int kc = 0; kc < 8; ++kc) {
    float4 a0 = xa[kc][0], a1 = xa[kc][1];
    xsq += a0.x * a0.x + a0.y * a0.y + a0.z * a0.z + a0.w * a0.w +
           a1.x * a1.x + a1.y * a1.y + a1.z * a1.z + a1.w * a1.w;
  }
  xsq += __shfl_xor(xsq, 16);
  xsq += __shfl_xor(xsq, 32);

  const uint4* cfp = (const uint4*)cfb;
  f32x4 acc = {0.f, 0.f, 0.f, 0.f};
#pragma unroll
  for (int kc = 0; kc < 8; ++kc) {
    union { unsigned int u[4]; short8v s; } xb, cf;
    float4 a0 = xa[kc][0], a1 = xa[kc][1];
    xb.u[0] = cvt_pk_bf16(a0.x, a0.y);
    xb.u[1] = cvt_pk_bf16(a0.z, a0.w);
    xb.u[2] = cvt_pk_bf16(a1.x, a1.y);
    xb.u[3] = cvt_pk_bf16(a1.z, a1.w);
    uint4 cw = cfp[kc * 64 + l];
    cf.u[0] = cw.x; cf.u[1] = cw.y; cf.u[2] = cw.z; cf.u[3] = cw.w;
    acc = __builtin_amdgcn_mfma_f32_16x16x32_bf16(cf.s, xb.s, acc, 0, 0, 0);
  }

  int slot = slotL[pl];
#pragma unroll
  for (int j = 0; j < 4; ++j) {
    int m = lg * 4 + j;
    float d2 = csql[m] - 2.f * acc[j] + xsq;
    Dmat[(size_t)m * NPTS + slot] = sqrtf(fmaxf(d2, 0.f));
  }
}

// Radix-select; bin location via wave-0 hierarchical find (no block scans).
__global__ void __launch_bounds__(512) k_select(const float* __restrict__ Dmat,
                                                const int* __restrict__ gcounts,
                                                const int* __restrict__ offsets,
                                                float* __restrict__ pos_stat,
                                                float* __restrict__ neg_stat) {
  __shared__ unsigned int keys[VMAX];
  __shared__ int hist[2048];
  __shared__ int bsel[2];
  __shared__ float wsumf[8];
  __shared__ int wsumi[8];
  int tid = threadIdx.x;
  int lane = tid & 63, wv = tid >> 6;
  int b = blockIdx.x;
  int ci = b >> 4, cl = b & 15;
  bool largest = (ci == cl);
  int cnt = gcounts[cl];
  if (cnt > VMAX) cnt = VMAX;
  int off = offsets[cl];
  const float* src = Dmat + (size_t)ci * NPTS + off;
  unsigned int inv = largest ? 0xFFFFFFFFu : 0u;
  for (int t = tid; t < cnt; t += 512) keys[t] = __float_as_uint(src[t]) ^ inv;
  __syncthreads();

  int target = KSEL;
  unsigned int pfx = 0;

  for (int u = tid; u < 2048; u += 512) hist[u] = 0;
  __syncthreads();
  for (int t = tid; t < cnt; t += 512) atomicAdd(&hist[keys[t] >> 21], 1);
  __syncthreads();
  if (tid < 64) {
    int own = 0;
#pragma unroll
    for (int j = 0; j < 32; ++j) own += hist[lane * 32 + j];
    int incl = own;
    for (int o = 1; o < 64; o <<= 1) { int n = __shfl_up(incl, o); if (lane >= o) incl += n; }
    int excl = incl - own;
    unsigned long long mk = __ballot(excl < target && target <= incl);
    int sel = __ffsll((unsigned long long)mk) - 1;
    if (lane == sel) {
      int run = excl;
      for (int j = 0; j < 32; ++j) {
        int h = hist[lane * 32 + j];
        if (run < target && target <= run + h) { bsel[0] = lane * 32 + j; bsel[1] = target - run; }
        run += h;
      }
    }
  }
  __syncthreads();
  pfx = ((unsigned int)bsel[0]) << 21; target = bsel[1];
  __syncthreads();

  for (int u = tid; u < 2048; u += 512) hist[u] = 0;
  __syncthreads();
  for (int t = tid; t < cnt; t += 512) {
    unsigned int k = keys[t];
    if ((k >> 21) == (pfx >> 21)) atomicAdd(&hist[(k >> 10) & 0x7FF], 1);
  }
  __syncthreads();
  if (tid < 64) {
    int own = 0;
#pragma unroll
    for (int j = 0; j < 32; ++j) own += hist[lane * 32 + j];
    int incl = own;
    for (int o = 1; o < 64; o <<= 1) { int n = __shfl_up(incl, o); if (lane >= o) incl += n; }
    int excl = incl - own;
    unsigned long long mk = __ballot(excl < target && target <= incl);
    int sel = __ffsll((unsigned long long)mk) - 1;
    if (lane == sel) {
      int run = excl;
      for (int j = 0; j < 32; ++j) {
        int h = hist[lane * 32 + j];
        if (run < target && target <= run + h) { bsel[0] = lane * 32 + j; bsel[1] = target - run; }
        run += h;
      }
    }
  }
  __syncthreads();
  pfx |= ((unsigned int)bsel[0]) << 10; target = bsel[1];
  __syncthreads();

  for (int u = tid; u < 1024; u += 512) hist[u] = 0;
  __syncthreads();
  for (int t = tid; t < cnt; t += 512) {
    unsigned int k = keys[t];
    if ((k >> 10) == (pfx >> 10)) atomicAdd(&hist[k & 0x3FF], 1);
  }
  __syncthreads();
  if (tid < 64) {
    int own = 0;
#pragma unroll
    for (int j = 0; j < 16; ++j) own += hist[lane * 16 + j];
    int incl = own;
    for (int o = 1; o < 64; o <<= 1) { int n = __shfl_up(incl, o); if (lane >= o) incl += n; }
    int excl = incl - own;
    unsigned long long mk = __ballot(excl < target && target <= incl);
    int sel = __ffsll((unsigned long long)mk) - 1;
    if (lane == sel) {
      int run = excl;
      for (int j = 0; j < 16; ++j) {
        int h = hist[lane * 16 + j];
        if (run < target && target <= run + h) { bsel[0] = lane * 16 + j; }
        run += h;
      }
    }
  }
  __syncthreads();
  unsigned int T = pfx | (unsigned int)bsel[0];
  float fT = __uint_as_float(T ^ inv);

  int nl = 0; float sl = 0.f;
  for (int t = tid; t < cnt; t += 512) {
    unsigned int k = keys[t];
    if (k < T) { nl++; sl += __uint_as_float(k ^ inv); }
  }
#pragma unroll
  for (int m = 1; m < 64; m <<= 1) { nl += __shfl_xor(nl, m); sl += __shfl_xor(sl, m); }
  if (lane == 0) { wsumi[wv] = nl; wsumf[wv] = sl; }
  __syncthreads();
  int n_less = 0; float s_less = 0.f;
#pragma unroll
  for (int w2 = 0; w2 < 8; ++w2) { n_less += wsumi[w2]; s_less += wsumf[w2]; }
  float mean = (s_less + (float)(KSEL - n_less) * fT) / (float)KSEL;
  __syncthreads();

  float sv = 0.f;
  for (int t = tid; t < cnt; t += 512) {
    unsigned int k = keys[t];
    if (k < T) { float d = __uint_as_float(k ^ inv) - mean; sv += d * d; }
  }
#pragma unroll
  for (int m = 1; m < 64; m <<= 1) sv += __shfl_xor(sv, m);
  if (lane == 0) wsumf[wv] = sv;
  __syncthreads();
  if (tid == 0) {
    float vs = 0.f;
#pragma unroll
    for (int w2 = 0; w2 < 8; ++w2) vs += wsumf[w2];
    float dT = fT - mean;
    float var = (vs + (float)(KSEL - n_less) * dT * dT) / (float)(KSEL - 1);
    if (largest) pos_stat[ci] = mean + 1.96f * sqrtf(var);
    else neg_stat[ci * 16 + cl] = mean - 1.96f * sqrtf(var);
  }
}

__global__ void __launch_bounds__(256) k_loss(const float* __restrict__ pos_stat,
                                              const float* __restrict__ neg_stat,
                                              float* __restrict__ out) {
  __shared__ float red[256];
  int t = threadIdx.x;
  int i = t >> 4, c = t & 15;
  float v = 0.f;
  if (i != c) v = fmaxf(1.0f + pos_stat[i] - neg_stat[t], 0.f);
  red[t] = v; __syncthreads();
  for (int st = 128; st > 0; st >>= 1) { if (t < st) red[t] += red[t + st]; __syncthreads(); }
  if (t == 0) out[0] = red[0];
}

extern "C" void kernel_launch(void* const* d_in, const int* in_sizes, int n_in,
                              void* d_out, int out_size, void* d_ws, size_t ws_size,
                              hipStream_t stream) {
  const float* x = (const float*)d_in[0];
  const int* y = (const int*)d_in[1];
  float* out = (float*)d_out;
  char* ws = (char*)d_ws;

  int* counts = (int*)(ws + 16384);
  int* offsets = (int*)(ws + 16512);
  float* csq = (float*)(ws + 16576);
  float* pos_stat = (float*)(ws + 16640);
  float* neg_stat = (float*)(ws + 16704);
  float* centers = (float*)(ws + 17728);
  int* bhist = (int*)(ws + 34112);
  unsigned short* cfb = (unsigned short*)(ws + 50688);
  float* Dmat = (float*)(ws + 65536);
  float* partials = (float*)(ws + 65536);   // [512][4096] = 8 MB, consumed pre-k_dist
  int* slots = (int*)(ws + 16842752);
  float* partial2 = (float*)(ws + 33554432);

  k_histrank<<<256, 256, 0, stream>>>(y, bhist, slots);
  k_scan<<<1, 256, 0, stream>>>(bhist, counts, offsets);
  k_accum<<<512, 256, 0, stream>>>(x, y, partials);
  k_reduce<<<128, 256, 0, stream>>>(partials, partial2);
  k_centers<<<16, 256, 0, stream>>>(partial2, counts, centers, csq, cfb);
  k_dist<<<1024, 256, 0, stream>>>(x, cfb, csq, slots, bhist, Dmat);
  k_select<<<256, 512, 0, stream>>>(Dmat, counts, offsets, pos_stat, neg_stat);
  k_loss<<<1, 256, 0, stream>>>(pos_stat, neg_stat, out);
}